// Round 2
// baseline (810.976 us; speedup 1.0000x reference)
//
#include <hip/hip_runtime.h>
#include <hip/hip_bf16.h>

#define D_FEAT 256
#define D4 (D_FEAT / 4)   // 64 float4 per row == one wave
#define EPS 1e-12f

// Build CSR row_ptr from sorted COO row array.
// Thread e (0..E inclusive) fills row_ptr[prev+1 .. curr] = e.
__global__ void build_row_ptr_kernel(const int* __restrict__ row,
                                     int* __restrict__ row_ptr,
                                     int E, int N) {
    int e = blockIdx.x * blockDim.x + threadIdx.x;
    if (e > E) return;
    int curr = (e == E) ? N : row[e];
    int prev = (e == 0) ? -1 : row[e - 1];
    for (int r = prev + 1; r <= curr; ++r) row_ptr[r] = e;
}

// Fused SpMM (CSR) + L2 normalize + accumulate.
// One wave (64 lanes) per output row; lane l owns float4 of dims [4l,4l+4).
// mode 0: out = x + h_norm          (layer 0, initializes accumulator)
// mode 1: out += h_norm             (layer 1)
// mode 2: out = (out + h_norm)*0.25 (layer 2, final average over 4 terms)
__global__ __launch_bounds__(256) void spmm_norm_kernel(
    const float* __restrict__ h_in,
    const float* __restrict__ vals,
    const int*   __restrict__ col,
    const int*   __restrict__ row_ptr,
    float* __restrict__ h_out,
    float* __restrict__ out,
    const float* __restrict__ x,
    int n_nodes, int mode)
{
    const int wave = threadIdx.x >> 6;         // 4 waves per block
    const int lane = threadIdx.x & 63;
    const int r = blockIdx.x * 4 + wave;
    if (r >= n_nodes) return;

    const int start = row_ptr[r];
    const int end   = row_ptr[r + 1];

    const float4* __restrict__ h4 = (const float4*)h_in;

    float ax = 0.f, ay = 0.f, az = 0.f, aw = 0.f;

    for (int base = start; base < end; base += 64) {
        const int n = min(64, end - base);
        float v = 0.f;
        int   c = 0;
        if (lane < n) {
            v = vals[base + lane];
            c = col[base + lane];
        }
        for (int j = 0; j < n; ++j) {
            const float vj = __shfl(v, j);
            const int   cj = __shfl(c, j);
            const float4 hr = h4[(long)cj * D4 + lane];
            ax += vj * hr.x;
            ay += vj * hr.y;
            az += vj * hr.z;
            aw += vj * hr.w;
        }
    }

    // wave-wide sum of squares for the row norm
    float s = ax * ax + ay * ay + az * az + aw * aw;
    #pragma unroll
    for (int off = 32; off; off >>= 1) s += __shfl_xor(s, off);

    const float scale = 1.0f / fmaxf(sqrtf(s), EPS);
    const float hx = ax * scale, hy = ay * scale, hz = az * scale, hw = aw * scale;

    const long idx = (long)r * D4 + lane;
    float4 hn; hn.x = hx; hn.y = hy; hn.z = hz; hn.w = hw;
    ((float4*)h_out)[idx] = hn;

    float4 prev;
    if (mode == 0) prev = ((const float4*)x)[idx];
    else           prev = ((const float4*)out)[idx];

    float ox = prev.x + hx, oy = prev.y + hy, oz = prev.z + hz, ow = prev.w + hw;
    if (mode == 2) { ox *= 0.25f; oy *= 0.25f; oz *= 0.25f; ow *= 0.25f; }

    float4 o; o.x = ox; o.y = oy; o.z = oz; o.w = ow;
    ((float4*)out)[idx] = o;
}

extern "C" void kernel_launch(void* const* d_in, const int* in_sizes, int n_in,
                              void* d_out, int out_size, void* d_ws, size_t ws_size,
                              hipStream_t stream) {
    const float* x    = (const float*)d_in[0];
    const float* vals = (const float*)d_in[1];
    const int*   row  = (const int*)d_in[2];
    const int*   col  = (const int*)d_in[3];
    float* out = (float*)d_out;

    const int N = in_sizes[0] / D_FEAT;   // 100000
    const int E = in_sizes[1];            // 1600000

    // workspace layout: row_ptr | h_a | h_b
    char* ws = (char*)d_ws;
    size_t rp_bytes = ((size_t)(N + 1) * sizeof(int) + 1023) & ~(size_t)1023;
    int*   row_ptr = (int*)ws;
    float* h_a = (float*)(ws + rp_bytes);
    float* h_b = (float*)(ws + rp_bytes + (size_t)N * D_FEAT * sizeof(float));

    // 1. build CSR offsets
    {
        const int threads = 256;
        const int blocks = (E + 1 + threads - 1) / threads;
        build_row_ptr_kernel<<<blocks, threads, 0, stream>>>(row, row_ptr, E, N);
    }

    // 2. three fused SpMM+normalize+accumulate layers
    const int blocks = (N + 3) / 4;  // 4 rows (waves) per 256-thread block
    // layer 0: h_a = norm(A @ x);  out = x + h_a
    spmm_norm_kernel<<<blocks, 256, 0, stream>>>(x,   vals, col, row_ptr, h_a, out, x, N, 0);
    // layer 1: h_b = norm(A @ h_a); out += h_b
    spmm_norm_kernel<<<blocks, 256, 0, stream>>>(h_a, vals, col, row_ptr, h_b, out, x, N, 1);
    // layer 2: h_a = norm(A @ h_b); out = (out + h_a) * 0.25
    spmm_norm_kernel<<<blocks, 256, 0, stream>>>(h_b, vals, col, row_ptr, h_a, out, x, N, 2);
}

// Round 4
// 465.062 us; speedup vs baseline: 1.7438x; 1.7438x over previous
//
#include <hip/hip_runtime.h>
#include <hip/hip_bf16.h>

#define D_FEAT 256
#define EPS 1e-12f

static __device__ __forceinline__ float bf2f(unsigned short u) {
    return __uint_as_float(((unsigned int)u) << 16);
}
static __device__ __forceinline__ unsigned short f2bf(float f) {
    unsigned int u = __float_as_uint(f);
    // round to nearest even
    unsigned int r = (u + 0x7fffu + ((u >> 16) & 1u)) >> 16;
    return (unsigned short)r;
}

// Build CSR row_ptr from sorted COO row array.
__global__ void build_row_ptr_kernel(const int* __restrict__ row,
                                     int* __restrict__ row_ptr,
                                     int E, int N) {
    int e = blockIdx.x * blockDim.x + threadIdx.x;
    if (e > E) return;
    int curr = (e == E) ? N : row[e];
    int prev = (e == 0) ? -1 : row[e - 1];
    for (int r = prev + 1; r <= curr; ++r) row_ptr[r] = e;
}

// fp32 -> bf16 cast, 4 elems per thread
__global__ __launch_bounds__(256) void cast_bf16_kernel(const float* __restrict__ in,
                                                        unsigned short* __restrict__ out,
                                                        int n4) {
    int i = blockIdx.x * blockDim.x + threadIdx.x;
    if (i >= n4) return;
    float4 f = ((const float4*)in)[i];
    ushort4 u;
    u.x = f2bf(f.x); u.y = f2bf(f.y); u.z = f2bf(f.z); u.w = f2bf(f.w);
    ((ushort4*)out)[i] = u;
}

// Fused SpMM (CSR, bf16 features) + L2 normalize + accumulate (fp32).
// One wave per output row; lane l owns dims [4l, 4l+4) (one ushort4 = 8B).
// mode 0: out = x + h_norm
// mode 1: out += h_norm
// mode 2: out = (out + h_norm)*0.25   (h_out write skipped via write_h=0)
__global__ __launch_bounds__(256) void spmm_norm_kernel(
    const unsigned short* __restrict__ h_in,   // bf16 [N][256]
    const float* __restrict__ vals,
    const int*   __restrict__ col,
    const int*   __restrict__ row_ptr,
    unsigned short* __restrict__ h_out,        // bf16 [N][256]
    float* __restrict__ out,
    const float* __restrict__ x,
    int n_nodes, int mode, int write_h)
{
    const int wave = threadIdx.x >> 6;         // 4 waves per block
    const int lane = threadIdx.x & 63;
    const int r = blockIdx.x * 4 + wave;
    if (r >= n_nodes) return;

    const int start = row_ptr[r];
    const int end   = row_ptr[r + 1];

    const ushort4* __restrict__ h4 = (const ushort4*)h_in;  // row stride 64 ushort4

    float ax = 0.f, ay = 0.f, az = 0.f, aw = 0.f;

    for (int base = start; base < end; base += 64) {
        const int n = min(64, end - base);
        float v = 0.f;
        int   c = 0;
        if (lane < n) {
            v = vals[base + lane];
            c = col[base + lane];
        }
        int j = 0;
        for (; j + 4 <= n; j += 4) {
            const int   c0 = __shfl(c, j + 0), c1 = __shfl(c, j + 1);
            const int   c2 = __shfl(c, j + 2), c3 = __shfl(c, j + 3);
            const float v0 = __shfl(v, j + 0), v1 = __shfl(v, j + 1);
            const float v2 = __shfl(v, j + 2), v3 = __shfl(v, j + 3);
            const ushort4 g0 = h4[(long)c0 * 64 + lane];
            const ushort4 g1 = h4[(long)c1 * 64 + lane];
            const ushort4 g2 = h4[(long)c2 * 64 + lane];
            const ushort4 g3 = h4[(long)c3 * 64 + lane];
            ax += v0 * bf2f(g0.x); ay += v0 * bf2f(g0.y);
            az += v0 * bf2f(g0.z); aw += v0 * bf2f(g0.w);
            ax += v1 * bf2f(g1.x); ay += v1 * bf2f(g1.y);
            az += v1 * bf2f(g1.z); aw += v1 * bf2f(g1.w);
            ax += v2 * bf2f(g2.x); ay += v2 * bf2f(g2.y);
            az += v2 * bf2f(g2.z); aw += v2 * bf2f(g2.w);
            ax += v3 * bf2f(g3.x); ay += v3 * bf2f(g3.y);
            az += v3 * bf2f(g3.z); aw += v3 * bf2f(g3.w);
        }
        for (; j < n; ++j) {
            const int   cj = __shfl(c, j);
            const float vj = __shfl(v, j);
            const ushort4 g = h4[(long)cj * 64 + lane];
            ax += vj * bf2f(g.x); ay += vj * bf2f(g.y);
            az += vj * bf2f(g.z); aw += vj * bf2f(g.w);
        }
    }

    // wave-wide sum of squares for the row norm
    float s = ax * ax + ay * ay + az * az + aw * aw;
    #pragma unroll
    for (int off = 32; off; off >>= 1) s += __shfl_xor(s, off);

    const float scale = 1.0f / fmaxf(sqrtf(s), EPS);
    const float hx = ax * scale, hy = ay * scale;
    const float hz = az * scale, hw = aw * scale;

    const long idx = (long)r * 64 + lane;
    if (write_h) {
        ushort4 hn;
        hn.x = f2bf(hx); hn.y = f2bf(hy); hn.z = f2bf(hz); hn.w = f2bf(hw);
        ((ushort4*)h_out)[idx] = hn;
    }

    float4 prev;
    if (mode == 0) prev = ((const float4*)x)[idx];
    else           prev = ((const float4*)out)[idx];

    float ox = prev.x + hx, oy = prev.y + hy, oz = prev.z + hz, ow = prev.w + hw;
    if (mode == 2) { ox *= 0.25f; oy *= 0.25f; oz *= 0.25f; ow *= 0.25f; }

    float4 o; o.x = ox; o.y = oy; o.z = oz; o.w = ow;
    ((float4*)out)[idx] = o;
}

extern "C" void kernel_launch(void* const* d_in, const int* in_sizes, int n_in,
                              void* d_out, int out_size, void* d_ws, size_t ws_size,
                              hipStream_t stream) {
    const float* x    = (const float*)d_in[0];
    const float* vals = (const float*)d_in[1];
    const int*   row  = (const int*)d_in[2];
    const int*   col  = (const int*)d_in[3];
    float* out = (float*)d_out;

    const int N = in_sizes[0] / D_FEAT;   // 100000
    const int E = in_sizes[1];            // 1600000

    // workspace layout: row_ptr | xb(bf16) | h_a(bf16) | h_b(bf16)
    char* ws = (char*)d_ws;
    const size_t rp_bytes = ((size_t)(N + 1) * sizeof(int) + 1023) & ~(size_t)1023;
    const size_t hbytes   = (size_t)N * D_FEAT * sizeof(unsigned short);
    int*            row_ptr = (int*)ws;
    unsigned short* xb  = (unsigned short*)(ws + rp_bytes);
    unsigned short* h_a = (unsigned short*)(ws + rp_bytes + hbytes);
    unsigned short* h_b = (unsigned short*)(ws + rp_bytes + 2 * hbytes);

    // 1. build CSR offsets
    {
        const int threads = 256;
        const int blocks = (E + 1 + threads - 1) / threads;
        build_row_ptr_kernel<<<blocks, threads, 0, stream>>>(row, row_ptr, E, N);
    }

    // 2. cast x -> bf16 for the layer-0 gather
    {
        const int n4 = N * D_FEAT / 4;
        cast_bf16_kernel<<<(n4 + 255) / 256, 256, 0, stream>>>(x, xb, n4);
    }

    // 3. three fused SpMM+normalize+accumulate layers
    const int blocks = (N + 3) / 4;  // 4 rows (waves) per 256-thread block
    // layer 0: h_a = norm(A @ x);  out = x + h_a
    spmm_norm_kernel<<<blocks, 256, 0, stream>>>(xb,  vals, col, row_ptr, h_a, out, x, N, 0, 1);
    // layer 1: h_b = norm(A @ h_a); out += h_b
    spmm_norm_kernel<<<blocks, 256, 0, stream>>>(h_a, vals, col, row_ptr, h_b, out, x, N, 1, 1);
    // layer 2: out = (out + norm(A @ h_b)) * 0.25
    spmm_norm_kernel<<<blocks, 256, 0, stream>>>(h_b, vals, col, row_ptr, h_a, out, x, N, 2, 0);
}

// Round 6
// 270.106 us; speedup vs baseline: 3.0024x; 1.7218x over previous
//
#include <hip/hip_runtime.h>
#include <hip/hip_bf16.h>

#define D_FEAT 256
#define EPS 1e-12f

// Build CSR row_ptr from sorted COO row array.
__global__ void build_row_ptr_kernel(const int* __restrict__ row,
                                     int* __restrict__ row_ptr,
                                     int E, int N) {
    int e = blockIdx.x * blockDim.x + threadIdx.x;
    if (e > E) return;
    int curr = (e == E) ? N : row[e];
    int prev = (e == 0) ? -1 : row[e - 1];
    for (int r = prev + 1; r <= curr; ++r) row_ptr[r] = e;
}

// Quantize fp32 rows -> biased uint8 (q = round(v/scale)+128) + per-row scale.
// One wave per row; lane l owns dims [4l, 4l+4).
__global__ __launch_bounds__(256) void quant_rows_kernel(
    const float* __restrict__ in,
    unsigned char* __restrict__ q,
    float* __restrict__ s,
    int n_rows)
{
    const int wave = threadIdx.x >> 6, lane = threadIdx.x & 63;
    const int r = blockIdx.x * 4 + wave;
    if (r >= n_rows) return;
    const long idx = (long)r * 64 + lane;
    const float4 f = ((const float4*)in)[idx];
    float m = fmaxf(fmaxf(fabsf(f.x), fabsf(f.y)), fmaxf(fabsf(f.z), fabsf(f.w)));
    #pragma unroll
    for (int off = 32; off; off >>= 1) m = fmaxf(m, __shfl_xor(m, off));
    const float mg  = fmaxf(m, 1e-30f);
    const float inv = 127.0f / mg;
    const unsigned int u0 = (unsigned int)(int)rintf(fmaf(f.x, inv, 128.0f));
    const unsigned int u1 = (unsigned int)(int)rintf(fmaf(f.y, inv, 128.0f));
    const unsigned int u2 = (unsigned int)(int)rintf(fmaf(f.z, inv, 128.0f));
    const unsigned int u3 = (unsigned int)(int)rintf(fmaf(f.w, inv, 128.0f));
    ((unsigned int*)q)[idx] = u0 | (u1 << 8) | (u2 << 16) | (u3 << 24);
    if (lane == 0) s[r] = mg * (1.0f / 127.0f);
}

// Fused SpMM (CSR, int8 features + per-row scale) + L2 normalize.
// One wave per output row; lane l owns dims [4l,4l+4) (one uint = 4B gather).
// acc_dim = sum_e w_e * q_e[dim] - 128 * sum_e w_e,  w_e = vals_e * s_in[col_e]
// mode 0/1: quantize h -> q_out/s_out
// mode 2:   out = 0.25 * (x + dq(q1) + dq(q2) + h)
__global__ __launch_bounds__(256) void spmm_q_kernel(
    const unsigned char* __restrict__ q_in,
    const float* __restrict__ s_in,
    const float* __restrict__ vals,
    const int*   __restrict__ col,
    const int*   __restrict__ row_ptr,
    unsigned char* __restrict__ q_out,
    float* __restrict__ s_out,
    const float* __restrict__ x,
    const unsigned char* __restrict__ q1p, const float* __restrict__ s1p,
    const unsigned char* __restrict__ q2p, const float* __restrict__ s2p,
    float* __restrict__ out,
    int n_nodes, int mode)
{
    const int wave = threadIdx.x >> 6, lane = threadIdx.x & 63;
    const int r = blockIdx.x * 4 + wave;
    if (r >= n_nodes) return;

    const int start = row_ptr[r];
    const int end   = row_ptr[r + 1];

    const unsigned int* __restrict__ qi = (const unsigned int*)q_in;

    float ax = 0.f, ay = 0.f, az = 0.f, aw = 0.f;
    float wsum = 0.f;

    for (int base = start; base < end; base += 64) {
        const int n = min(64, end - base);
        float w = 0.f;
        int   c = 0;
        if (lane < n) {
            c = col[base + lane];
            w = vals[base + lane] * s_in[c];   // scale table: L2-resident 400KB
        }
        wsum += w;
        int j = 0;
        for (; j + 4 <= n; j += 4) {
            const int   c0 = __shfl(c, j + 0), c1 = __shfl(c, j + 1);
            const int   c2 = __shfl(c, j + 2), c3 = __shfl(c, j + 3);
            const float w0 = __shfl(w, j + 0), w1 = __shfl(w, j + 1);
            const float w2 = __shfl(w, j + 2), w3 = __shfl(w, j + 3);
            const unsigned int g0 = qi[(long)c0 * 64 + lane];
            const unsigned int g1 = qi[(long)c1 * 64 + lane];
            const unsigned int g2 = qi[(long)c2 * 64 + lane];
            const unsigned int g3 = qi[(long)c3 * 64 + lane];
            ax += w0 * (float)(g0 & 0xff);         ay += w0 * (float)((g0 >> 8) & 0xff);
            az += w0 * (float)((g0 >> 16) & 0xff); aw += w0 * (float)(g0 >> 24);
            ax += w1 * (float)(g1 & 0xff);         ay += w1 * (float)((g1 >> 8) & 0xff);
            az += w1 * (float)((g1 >> 16) & 0xff); aw += w1 * (float)(g1 >> 24);
            ax += w2 * (float)(g2 & 0xff);         ay += w2 * (float)((g2 >> 8) & 0xff);
            az += w2 * (float)((g2 >> 16) & 0xff); aw += w2 * (float)(g2 >> 24);
            ax += w3 * (float)(g3 & 0xff);         ay += w3 * (float)((g3 >> 8) & 0xff);
            az += w3 * (float)((g3 >> 16) & 0xff); aw += w3 * (float)(g3 >> 24);
        }
        for (; j < n; ++j) {
            const int   cj = __shfl(c, j);
            const float wj = __shfl(w, j);
            const unsigned int g = qi[(long)cj * 64 + lane];
            ax += wj * (float)(g & 0xff);         ay += wj * (float)((g >> 8) & 0xff);
            az += wj * (float)((g >> 16) & 0xff); aw += wj * (float)(g >> 24);
        }
    }

    // total edge weight (for the -128 bias term)
    float ws = wsum;
    #pragma unroll
    for (int off = 32; off; off >>= 1) ws += __shfl_xor(ws, off);
    const float bias = 128.0f * ws;

    const float px = ax - bias, py = ay - bias, pz = az - bias, pw = aw - bias;

    // wave-wide sum of squares for the row norm
    float s = px * px + py * py + pz * pz + pw * pw;
    #pragma unroll
    for (int off = 32; off; off >>= 1) s += __shfl_xor(s, off);

    const float sc = 1.0f / fmaxf(sqrtf(s), EPS);
    const float hx = px * sc, hy = py * sc, hz = pz * sc, hw = pw * sc;

    const long idx = (long)r * 64 + lane;

    if (mode < 2) {
        // quantize normalized h for the next layer's gather
        float m = fmaxf(fmaxf(fabsf(hx), fabsf(hy)), fmaxf(fabsf(hz), fabsf(hw)));
        #pragma unroll
        for (int off = 32; off; off >>= 1) m = fmaxf(m, __shfl_xor(m, off));
        const float mg  = fmaxf(m, 1e-30f);
        const float inv = 127.0f / mg;
        const unsigned int u0 = (unsigned int)(int)rintf(fmaf(hx, inv, 128.0f));
        const unsigned int u1 = (unsigned int)(int)rintf(fmaf(hy, inv, 128.0f));
        const unsigned int u2 = (unsigned int)(int)rintf(fmaf(hz, inv, 128.0f));
        const unsigned int u3 = (unsigned int)(int)rintf(fmaf(hw, inv, 128.0f));
        ((unsigned int*)q_out)[idx] = u0 | (u1 << 8) | (u2 << 16) | (u3 << 24);
        if (lane == 0) s_out[r] = mg * (1.0f / 127.0f);
    } else {
        // final combine: out = 0.25*(x + dq(q1) + dq(q2) + h)
        const float4 xv = ((const float4*)x)[idx];
        const unsigned int g1 = ((const unsigned int*)q1p)[idx];
        const unsigned int g2 = ((const unsigned int*)q2p)[idx];
        const float sc1 = s1p[r], sc2 = s2p[r];
        float4 o;
        o.x = 0.25f * (xv.x + ((float)(g1 & 0xff)         - 128.f) * sc1
                            + ((float)(g2 & 0xff)         - 128.f) * sc2 + hx);
        o.y = 0.25f * (xv.y + ((float)((g1 >> 8) & 0xff)  - 128.f) * sc1
                            + ((float)((g2 >> 8) & 0xff)  - 128.f) * sc2 + hy);
        o.z = 0.25f * (xv.z + ((float)((g1 >> 16) & 0xff) - 128.f) * sc1
                            + ((float)((g2 >> 16) & 0xff) - 128.f) * sc2 + hz);
        o.w = 0.25f * (xv.w + ((float)(g1 >> 24)          - 128.f) * sc1
                            + ((float)(g2 >> 24)          - 128.f) * sc2 + hw);
        ((float4*)out)[idx] = o;
    }
}

extern "C" void kernel_launch(void* const* d_in, const int* in_sizes, int n_in,
                              void* d_out, int out_size, void* d_ws, size_t ws_size,
                              hipStream_t stream) {
    const float* x    = (const float*)d_in[0];
    const float* vals = (const float*)d_in[1];
    const int*   row  = (const int*)d_in[2];
    const int*   col  = (const int*)d_in[3];
    float* out = (float*)d_out;

    const int N = in_sizes[0] / D_FEAT;   // 100000
    const int E = in_sizes[1];            // 1600000

    // workspace: row_ptr | xq | sx | q1 | s1 | q2 | s2   (all 1KB-aligned)
    auto align1k = [](size_t v) { return (v + 1023) & ~(size_t)1023; };
    const size_t rp_bytes = align1k((size_t)(N + 1) * sizeof(int));
    const size_t qbytes   = align1k((size_t)N * D_FEAT);           // uint8 rows
    const size_t sbytes   = align1k((size_t)N * sizeof(float));    // per-row scale
    char* ws = (char*)d_ws;
    int*           row_ptr = (int*)ws;                      ws += rp_bytes;
    unsigned char* xq = (unsigned char*)ws;                 ws += qbytes;
    float*         sx = (float*)ws;                         ws += sbytes;
    unsigned char* q1 = (unsigned char*)ws;                 ws += qbytes;
    float*         s1 = (float*)ws;                         ws += sbytes;
    unsigned char* q2 = (unsigned char*)ws;                 ws += qbytes;
    float*         s2 = (float*)ws;

    // 1. CSR offsets
    {
        const int threads = 256;
        const int blocks = (E + 1 + threads - 1) / threads;
        build_row_ptr_kernel<<<blocks, threads, 0, stream>>>(row, row_ptr, E, N);
    }

    const int blocks = (N + 3) / 4;  // one wave per row, 4 waves per block

    // 2. quantize x for the layer-0 gather
    quant_rows_kernel<<<blocks, 256, 0, stream>>>(x, xq, sx, N);

    // 3. three fused layers
    // L0: h1 = norm(A @ x)  -> q1/s1
    spmm_q_kernel<<<blocks, 256, 0, stream>>>(xq, sx, vals, col, row_ptr,
                                              q1, s1, x, q1, s1, q2, s2, out, N, 0);
    // L1: h2 = norm(A @ h1) -> q2/s2
    spmm_q_kernel<<<blocks, 256, 0, stream>>>(q1, s1, vals, col, row_ptr,
                                              q2, s2, x, q1, s1, q2, s2, out, N, 1);
    // L2: out = 0.25*(x + h1 + h2 + norm(A @ h2))
    spmm_q_kernel<<<blocks, 256, 0, stream>>>(q2, s2, vals, col, row_ptr,
                                              q2, s2, x, q1, s1, q2, s2, out, N, 2);
}